// Round 9
// baseline (142.354 us; speedup 1.0000x reference)
//
#include <hip/hip_runtime.h>

#define N_ATOMS 100000
#define N_EDGES 625000
#define N_MOL   1000
#define EMB_ATOM 256
#define EMB_EDGE 128

typedef float f32x4 __attribute__((ext_vector_type(4)));

__device__ __forceinline__ float dot4(f32x4 a, f32x4 b) {
    return a.x * b.x + a.y * b.y + a.z * b.z + a.w * b.w;
}

// Vectorized zero of d_out (301000 floats = 75250 f32x4 exactly).
__global__ __launch_bounds__(256) void zero_kernel(f32x4* __restrict__ p, int n4)
{
    const int i = blockIdx.x * blockDim.x + threadIdx.x;
    if (i < n4) p[i] = (f32x4)(0.f, 0.f, 0.f, 0.f);
}

// Fused kernel, deeper MLP than R8: 256B/thread in flight.
//
// Forces: 8 lanes per edge row, 4 groups -> 32 edges/wave. All 16 NT loads
// (4 groups x 4 f32x4) issued up-front with static indexing, idx/V_st
// prefetched, then per group: dot + 3-stage butterfly (reduces 8 edges at
// once) + 3-lane atomic scatter.
// Waves: ceil(625000/32) = 19532 -> 4883 blocks exactly.
//
// Energy: 16 lanes per atom row, 4 groups -> 16 atoms/wave. 16 NT loads
// up-front, 4-stage butterfly per group (4 atoms at once), sub==0 atomic.
// Waves: 100000/16 = 6250 -> 1563 blocks (2 tail waves early-return).
#define FWAVES  ((N_EDGES + 31) / 32)            // 19532
#define FBLOCKS ((FWAVES + 3) / 4)               // 4883
#define EWAVES  (N_ATOMS / 16)                   // 6250
#define EBLOCKS ((EWAVES + 3) / 4)               // 1563

__global__ __launch_bounds__(256) void fused_kernel(
    const float* __restrict__ h_energy,
    const float* __restrict__ h_forces,
    const float* __restrict__ V_st,
    const int*   __restrict__ idx_t,
    const int*   __restrict__ batch_idx,
    const float* __restrict__ W_energy,
    const float* __restrict__ W_forces,
    const float* __restrict__ b_forces,
    float*       __restrict__ y_out,
    float*       __restrict__ force_out)
{
    const int lane = threadIdx.x & 63;

    if (blockIdx.x < FBLOCKS) {
        // ---------------- forces ----------------
        const int w    = blockIdx.x * 4 + (threadIdx.x >> 6);  // wave id
        const int slot = lane >> 3;      // 0..7 : edge slot within wave
        const int sub  = lane & 7;       // 0..7 : position within edge row

        const f32x4* wf   = reinterpret_cast<const f32x4*>(W_forces);
        const f32x4* base = reinterpret_cast<const f32x4*>(h_forces); // row = 32 f32x4

        f32x4 b0 = wf[sub + 0];
        f32x4 b1 = wf[sub + 8];
        f32x4 b2 = wf[sub + 16];
        f32x4 b3 = wf[sub + 24];
        const float bias = b_forces[0];

        int  e[4];
        bool ok[4];
        f32x4 a[4][4];
        const f32x4 z = (f32x4)(0.f, 0.f, 0.f, 0.f);

        #pragma unroll
        for (int g = 0; g < 4; ++g) {
            e[g]  = w * 32 + g * 8 + slot;
            ok[g] = (e[g] < N_EDGES);
            const f32x4* row = base + (size_t)e[g] * 32;
            a[g][0] = ok[g] ? __builtin_nontemporal_load(row + sub + 0)  : z;
            a[g][1] = ok[g] ? __builtin_nontemporal_load(row + sub + 8)  : z;
            a[g][2] = ok[g] ? __builtin_nontemporal_load(row + sub + 16) : z;
            a[g][3] = ok[g] ? __builtin_nontemporal_load(row + sub + 24) : z;
        }

        // Prefetch scatter metadata so its latency hides under the reduces.
        int   t[4];
        float v[4];
        #pragma unroll
        for (int g = 0; g < 4; ++g) {
            if (ok[g] && sub < 3) {
                t[g] = idx_t[e[g]];
                v[g] = V_st[(size_t)e[g] * 3 + sub];
            } else { t[g] = 0; v[g] = 0.f; }
        }

        #pragma unroll
        for (int g = 0; g < 4; ++g) {
            float s = dot4(a[g][0], b0) + dot4(a[g][1], b1)
                    + dot4(a[g][2], b2) + dot4(a[g][3], b3);
            // reduce within each 8-lane slot: 8 edges of the wave at once
            s += __shfl_xor(s, 1, 64);
            s += __shfl_xor(s, 2, 64);
            s += __shfl_xor(s, 4, 64);
            if (ok[g] && sub < 3)
                atomicAdd(&force_out[(size_t)t[g] * 3 + sub], (s + bias) * v[g]);
        }
    } else if (blockIdx.x < FBLOCKS + EBLOCKS) {
        // ---------------- energy ----------------
        const int w = (blockIdx.x - FBLOCKS) * 4 + (threadIdx.x >> 6);
        if (w >= EWAVES) return;         // wave-uniform, no barriers in kernel
        const int slot = lane >> 4;      // 0..3 : atom slot
        const int sub  = lane & 15;      // 0..15: position within atom row

        const f32x4* we   = reinterpret_cast<const f32x4*>(W_energy);
        const f32x4* base = reinterpret_cast<const f32x4*>(h_energy); // row = 64 f32x4

        f32x4 b0 = we[sub + 0];
        f32x4 b1 = we[sub + 16];
        f32x4 b2 = we[sub + 32];
        f32x4 b3 = we[sub + 48];

        f32x4 a[4][4];
        #pragma unroll
        for (int g = 0; g < 4; ++g) {
            const int atom = w * 16 + g * 4 + slot;   // < 100000 (6250 waves exact)
            const f32x4* row = base + (size_t)atom * 64;
            a[g][0] = __builtin_nontemporal_load(row + sub + 0);
            a[g][1] = __builtin_nontemporal_load(row + sub + 16);
            a[g][2] = __builtin_nontemporal_load(row + sub + 32);
            a[g][3] = __builtin_nontemporal_load(row + sub + 48);
        }

        int mol[4];
        #pragma unroll
        for (int g = 0; g < 4; ++g) {
            if (sub == 0) mol[g] = batch_idx[w * 16 + g * 4 + slot];
            else          mol[g] = 0;
        }

        #pragma unroll
        for (int g = 0; g < 4; ++g) {
            float s = dot4(a[g][0], b0) + dot4(a[g][1], b1)
                    + dot4(a[g][2], b2) + dot4(a[g][3], b3);
            // reduce within each 16-lane slot: 4 atoms at once
            s += __shfl_xor(s, 1, 64);
            s += __shfl_xor(s, 2, 64);
            s += __shfl_xor(s, 4, 64);
            s += __shfl_xor(s, 8, 64);
            if (sub == 0) atomicAdd(&y_out[mol[g]], s);
        }
    }
}

extern "C" void kernel_launch(void* const* d_in, const int* in_sizes, int n_in,
                              void* d_out, int out_size, void* d_ws, size_t ws_size,
                              hipStream_t stream) {
    const float* h_energy  = (const float*)d_in[0];
    const float* h_forces  = (const float*)d_in[1];
    const float* V_st      = (const float*)d_in[2];
    const int*   idx_t     = (const int*)d_in[3];
    const int*   batch_idx = (const int*)d_in[4];
    const float* W_energy  = (const float*)d_in[5];
    const float* W_forces  = (const float*)d_in[6];
    const float* b_forces  = (const float*)d_in[7];

    float* y_out     = (float*)d_out;            // N_MOL floats
    float* force_out = (float*)d_out + N_MOL;    // N_ATOMS*3 floats

    // Zero d_out (atomic accumulation needs zeroed output each call).
    const int n4 = out_size / 4;                 // 75250 exactly
    zero_kernel<<<(n4 + 255) / 256, 256, 0, stream>>>((f32x4*)d_out, n4);

    // One fused kernel: 4883 forces blocks + 1563 energy blocks.
    fused_kernel<<<FBLOCKS + EBLOCKS, 256, 0, stream>>>(
        h_energy, h_forces, V_st, idx_t, batch_idx,
        W_energy, W_forces, b_forces, y_out, force_out);
}